// Round 9
// baseline (876.180 us; speedup 1.0000x reference)
//
#include <hip/hip_runtime.h>
#include <hip/hip_fp16.h>
#include <math.h>

#define NH 5
#define NC 64
#define ED 16
#define HC 320   // NH*NC
#define HP 8     // padded head stride (5 used + 3 pad) -> hbuf[N][64][8]
#define CH 32    // CSR slots per wave window in gat_fused

typedef _Float16 h2  __attribute__((ext_vector_type(2)));
typedef _Float16 v8h __attribute__((ext_vector_type(8)));
typedef float    v4f __attribute__((ext_vector_type(4)));

// ---------------- DPP wave64 sum -> uniform scalar via lane 63 ----------------
template<int ctrl, int rmask>
__device__ __forceinline__ float dpp_add(float x) {
    int y = __builtin_amdgcn_update_dpp(0, __float_as_int(x), ctrl, rmask, 0xf, true);
    return x + __int_as_float(y);
}
__device__ __forceinline__ float wave_sum_all(float x) {
    x = dpp_add<0xb1, 0xf>(x);   // quad_perm xor1
    x = dpp_add<0x4e, 0xf>(x);   // quad_perm xor2
    x = dpp_add<0x114, 0xf>(x);  // row_shr:4
    x = dpp_add<0x118, 0xf>(x);  // row_shr:8
    x = dpp_add<0x142, 0xa>(x);  // row_bcast:15 -> rows 1,3
    x = dpp_add<0x143, 0xc>(x);  // row_bcast:31 -> rows 2,3 ; lane 63 = total
    return __int_as_float(__builtin_amdgcn_readlane(__float_as_int(x), 63));
}

// ---------------- preprocessing ----------------

__global__ void count_kernel(const int* __restrict__ dst, int* __restrict__ cnt, int E) {
    int t = blockIdx.x * blockDim.x + threadIdx.x;
    if (t >= E) return;
    atomicAdd(&cnt[dst[t]], 1);
}

__global__ void scan_kernel(const int* __restrict__ cnt, int* __restrict__ offsets,
                            int* __restrict__ cursor, int N) {
    __shared__ int sums[1024];
    int t = threadIdx.x;
    int chunk = (N + 1023) / 1024;
    int beg = t * chunk;
    int end = min(beg + chunk, N);
    int s = 0;
    for (int i = beg; i < end; ++i) s += cnt[i] + 1;
    sums[t] = s;
    __syncthreads();
    for (int o = 1; o < 1024; o <<= 1) {
        int v = (t >= o) ? sums[t - o] : 0;
        __syncthreads();
        sums[t] += v;
        __syncthreads();
    }
    int run = (t > 0) ? sums[t - 1] : 0;
    for (int i = beg; i < end; ++i) {
        offsets[i] = run; cursor[i] = run;
        run += cnt[i] + 1;
    }
    if (t == 0) offsets[N] = sums[1023];
}

__global__ void scatter_kernel(const int* __restrict__ src, const int* __restrict__ dst,
                               int* __restrict__ cursor, int2* __restrict__ recs, int N, int E) {
    int t = blockIdx.x * blockDim.x + threadIdx.x;
    if (t >= E + N) return;
    int d, s;
    if (t < E) { d = dst[t]; s = src[t]; }
    else       { d = t - E; s = t - E; }
    int pos = atomicAdd(&cursor[d], 1);
    recs[pos] = make_int2(s, t);
}

__global__ void loop_from_csr(const int* __restrict__ offsets, const int2* __restrict__ recs,
                              const float* __restrict__ ea, float* __restrict__ loop,
                              int N, int E) {
    int t = blockIdx.x * blockDim.x + threadIdx.x;
    int n = t >> 4, k = t & 15;
    if (n >= N) return;
    int beg = offsets[n], end = offsets[n + 1];
    float s = 0.f; int c = 0;
    for (int j = beg; j < end; ++j) {
        int y = recs[j].y;
        if (y < E) { s += ea[(size_t)y * ED + k]; ++c; }
    }
    loop[(size_t)n * ED + k] = s / (float)max(c, 1);
}

__global__ void reorder_ea(const int2* __restrict__ recs, const float* __restrict__ ea,
                           const float* __restrict__ loop, h2* __restrict__ easrt,
                           int R, int E) {
    int t = blockIdx.x * blockDim.x + threadIdx.x;
    int slot = t >> 3, k2 = t & 7;
    if (slot >= R) return;
    int y = recs[slot].y;
    const float2* sp = (const float2*)((y < E) ? ea + (size_t)y * ED : loop + (size_t)(y - E) * ED);
    float2 f = sp[k2];
    h2 o; o.x = (_Float16)f.x; o.y = (_Float16)f.y;
    easrt[(size_t)slot * 8 + k2] = o;
}

__global__ void win_start_kernel(const int* __restrict__ offsets, int* __restrict__ winStart, int N) {
    int i = blockIdx.x * blockDim.x + threadIdx.x;
    if (i >= N) return;
    atomicMin(&winStart[offsets[i] / CH], i);
}

__global__ void cvt_f16(const float* __restrict__ in, _Float16* __restrict__ out, int n) {
    int i = blockIdx.x * blockDim.x + threadIdx.x;
    if (i < n) out[i] = (_Float16)in[i];
}

// W[K][320] -> Wt[320][K] fp16
__global__ void transpose_w(const float* __restrict__ W, _Float16* __restrict__ Wt, int K) {
    int t = blockIdx.x * blockDim.x + threadIdx.x;
    if (t >= 320 * K) return;
    int k = t / 320, n = t % 320;
    Wt[(size_t)n * K + k] = (_Float16)W[t];
}

// ---------------- MFMA GEMM: hbuf[M][64][8] (head-contiguous) = A @ Wt^T + bias ----------
// wave computes 16 rows x 320 cols; LDS transpose epilogue for coalesced padded stores.
__global__ __launch_bounds__(256) void gemm_mfma(const _Float16* __restrict__ A,
                                                 const _Float16* __restrict__ Bt,
                                                 const float* __restrict__ bias,
                                                 _Float16* __restrict__ Cout, int M, int K) {
    __shared__ _Float16 lds[4][8][NC * HP];   // 32 KB
    int lane = threadIdx.x & 63;
    int wave = threadIdx.x >> 6;
    int m = lane & 15, quad = lane >> 4;
    int rowBase = (blockIdx.x * 4 + wave) * 16;
    bool active = rowBase < M;

    v4f acc[20];
#pragma unroll
    for (int c = 0; c < 20; ++c) acc[c] = (v4f){0.f, 0.f, 0.f, 0.f};

    if (active) {
        for (int k0 = 0; k0 < K; k0 += 32) {
            v8h a = *(const v8h*)&A[(size_t)(rowBase + m) * K + k0 + quad * 8];
#pragma unroll
            for (int c = 0; c < 20; ++c) {
                v8h b = *(const v8h*)&Bt[(size_t)(c * 16 + m) * K + k0 + quad * 8];
                acc[c] = __builtin_amdgcn_mfma_f32_16x16x32_f16(a, b, acc[c], 0, 0, 0);
            }
        }
    }
    // C/D: col = c*16+m, row = quad*4+r.  Write rows [pass*8, pass*8+8) via LDS.
#pragma unroll
    for (int pass = 0; pass < 2; ++pass) {
        if (active && (quad >> 1) == pass) {
#pragma unroll
            for (int c = 0; c < 20; ++c) {
                int cc = c * 16 + m;
                int idx = (cc & 63) * HP + (cc >> 6);
                float bb = bias[cc];
#pragma unroll
                for (int r = 0; r < 4; ++r)
                    lds[wave][(quad & 1) * 4 + r][idx] = (_Float16)(acc[c][r] + bb);
            }
        }
        __syncthreads();
        if (active) {
#pragma unroll
            for (int rr = 0; rr < 8; ++rr) {
                v8h v = *(const v8h*)&lds[wave][rr][lane * HP];
                *(v8h*)&Cout[(size_t)(rowBase + pass * 8 + rr) * (NC * HP) + lane * HP] = v;
            }
        }
        __syncthreads();
    }
}

// ---------------- fused logits + single-pass softmax + aggregate + ELU ----------------
__global__ __launch_bounds__(256) void gat_fused(const _Float16* __restrict__ hbuf, // [N][64][8]
                                                 const int* __restrict__ offsets,
                                                 const int2* __restrict__ recs,
                                                 const h2* __restrict__ easrt,
                                                 const int* __restrict__ winStart,
                                                 const float* __restrict__ We,
                                                 const float* __restrict__ att,
                                                 const float* __restrict__ bias,
                                                 _Float16* __restrict__ outH,
                                                 float* __restrict__ outF,
                                                 int N, int R) {
    int lane = threadIdx.x & 63;
    int wave = (blockIdx.x * blockDim.x + threadIdx.x) >> 6;
    int totalWaves = (gridDim.x * blockDim.x) >> 6;

    // pack We slice: we2[k2*NH+h] = {We[2k2][h][lane], We[2k2+1][h][lane]}
    h2 we2[8 * NH];
#pragma unroll
    for (int k2 = 0; k2 < 8; ++k2)
#pragma unroll
        for (int h = 0; h < NH; ++h) {
            h2 w;
            w.x = (_Float16)We[(2 * k2) * HC + h * NC + lane];
            w.y = (_Float16)We[(2 * k2 + 1) * HC + h * NC + lane];
            we2[k2 * NH + h] = w;
        }
    const float L2E = 1.4426950408889634f;   // fold log2(e) into att so exp -> exp2
    float attc6[NH], attc4[NH];
#pragma unroll
    for (int h = 0; h < NH; ++h) {
        float a = att[h * NC + lane];
        attc6[h] = 0.6f * a * L2E;
        attc4[h] = 0.4f * a * L2E;
    }
    float bc = bias[lane];

    for (int w = wave; w * CH < R; w += totalWaves) {
        int i = winStart[w];
        if (i >= N) continue;
        int winEnd = w * CH + CH;
        for (; i < N; ++i) {
            int beg = offsets[i];
            if (beg >= winEnd) break;
            int end = offsets[i + 1];

            v8h hdv = *(const v8h*)&hbuf[(size_t)i * (NC * HP) + lane * HP];
            float hd[NH];
#pragma unroll
            for (int h = 0; h < NH; ++h) hd[h] = (float)hdv[h];

            float l[NH] = {}, acc[NH] = {};
            for (int t = beg; t < end; ++t) {
                int tu = __builtin_amdgcn_readfirstlane(t);   // wave-uniform -> s_load path
                int src = recs[tu].x;
                const h2* ap = easrt + (size_t)tu * 8;
                h2 a[8];
#pragma unroll
                for (int k2 = 0; k2 < 8; ++k2) a[k2] = ap[k2];
                v8h hsv = *(const v8h*)&hbuf[(size_t)src * (NC * HP) + lane * HP];
                float hs[NH];
#pragma unroll
                for (int h = 0; h < NH; ++h) hs[h] = (float)hsv[h];

                float p[NH];
#pragma unroll
                for (int h = 0; h < NH; ++h) {
                    float v = hs[h] + hd[h];
#pragma unroll
                    for (int k2 = 0; k2 < 8; ++k2)
                        v = __builtin_amdgcn_fdot2(a[k2], we2[k2 * NH + h], v, false);
                    // leaky_relu(0.2)(v)*att*log2e = v*attc6 + |v|*attc4
                    p[h] = fmaf(fabsf(v), attc4[h], v * attc6[h]);
                }
#pragma unroll
                for (int h = 0; h < NH; ++h) {
                    float pe = exp2f(wave_sum_all(p[h]));
                    l[h] += pe;
                    acc[h] = fmaf(pe, hs[h], acc[h]);
                }
            }
            float o = 0.f;
#pragma unroll
            for (int h = 0; h < NH; ++h) o += acc[h] / l[h];
            o = o * 0.2f + bc;
            o = o > 0.f ? o : expm1f(o);
            if (outF) outF[(size_t)i * NC + lane] = o;
            else      outH[(size_t)i * NC + lane] = (_Float16)o;
        }
    }
}

// ---------------- launch ----------------
extern "C" void kernel_launch(void* const* d_in, const int* in_sizes, int n_in,
                              void* d_out, int out_size, void* d_ws, size_t ws_size,
                              hipStream_t stream) {
    const float* x     = (const float*)d_in[0];
    const int*   ei    = (const int*)d_in[1];
    const float* ea    = (const float*)d_in[2];
    const float* W0    = (const float*)d_in[3];
    const float* b0    = (const float*)d_in[4];
    const float* We0   = (const float*)d_in[5];
    const float* att0  = (const float*)d_in[6];
    const float* bias0 = (const float*)d_in[7];
    const float* W12   = (const float*)d_in[8];
    const float* b12   = (const float*)d_in[9];
    const float* We12  = (const float*)d_in[10];
    const float* att12 = (const float*)d_in[11];
    const float* bias12= (const float*)d_in[12];

    int N = in_sizes[0] / 128;
    int E = in_sizes[1] / 2;
    int R = E + N;
    int numWin = (R + CH - 1) / CH;
    const int* srcArr = ei;
    const int* dstArr = ei + E;

    char* ws = (char*)d_ws;
    size_t off = 0;
    auto alloc = [&](size_t bytes) -> void* {
        void* p = ws + off;
        off = (off + bytes + 255) & ~(size_t)255;
        return p;
    };
    int*      cnt     = (int*)alloc((size_t)N * 4);
    int*      offsets = (int*)alloc((size_t)(N + 1) * 4);
    int*      cursor  = (int*)alloc((size_t)N * 4);
    int2*     recs    = (int2*)alloc((size_t)R * 8);
    float*    loop    = (float*)alloc((size_t)N * ED * 4);
    _Float16* hbuf    = (_Float16*)alloc((size_t)N * NC * HP * 2);   // [N][64][8]
    _Float16* acth    = (_Float16*)alloc((size_t)N * NC * 2);
    _Float16* xh      = (_Float16*)alloc((size_t)N * 128 * 2);
    _Float16* Wth0    = (_Float16*)alloc((size_t)320 * 128 * 2);
    _Float16* Wth1    = (_Float16*)alloc((size_t)320 * 64 * 2);
    _Float16* Wth2    = (_Float16*)alloc((size_t)320 * 64 * 2);
    int*      winStart= (int*)alloc((size_t)(numWin + 1) * 4);
    h2*       easrt   = (h2*)alloc((size_t)R * 32);

    (void)hipMemsetAsync(cnt, 0, (size_t)N * 4, stream);
    (void)hipMemsetAsync(winStart, 0x7f, (size_t)(numWin + 1) * 4, stream);
    count_kernel<<<(E + 255) / 256, 256, 0, stream>>>(dstArr, cnt, E);
    scan_kernel<<<1, 1024, 0, stream>>>(cnt, offsets, cursor, N);
    scatter_kernel<<<(E + N + 255) / 256, 256, 0, stream>>>(srcArr, dstArr, cursor, recs, N, E);
    loop_from_csr<<<((size_t)N * ED + 255) / 256, 256, 0, stream>>>(offsets, recs, ea, loop, N, E);
    reorder_ea<<<((size_t)R * 8 + 255) / 256, 256, 0, stream>>>(recs, ea, loop, easrt, R, E);
    win_start_kernel<<<(N + 255) / 256, 256, 0, stream>>>(offsets, winStart, N);
    cvt_f16<<<((size_t)N * 128 + 255) / 256, 256, 0, stream>>>(x, xh, N * 128);
    transpose_w<<<(320 * 128 + 255) / 256, 256, 0, stream>>>(W0, Wth0, 128);
    transpose_w<<<(320 * 64 + 255) / 256, 256, 0, stream>>>(W12, Wth1, 64);
    transpose_w<<<(320 * 64 + 255) / 256, 256, 0, stream>>>(W12 + 64 * HC, Wth2, 64);

    float* dout = (float*)d_out;
    int gemmBlocks = (N / 16 + 3) / 4 + 1;
    int fusedBlocks = 2048;

    const _Float16* As[3]  = {xh, acth, acth};
    const _Float16* Bts[3] = {Wth0, Wth1, Wth2};
    int Ks[3] = {128, 64, 64};
    const float* bs[3]   = {b0, b12, b12 + HC};
    const float* Wes[3]  = {We0, We12, We12 + ED * HC};
    const float* atts[3] = {att0, att12, att12 + NH * NC};
    const float* bis[3]  = {bias0, bias12, bias12 + NC};
    for (int layer = 0; layer < 3; ++layer) {
        gemm_mfma<<<gemmBlocks, 256, 0, stream>>>(As[layer], Bts[layer], bs[layer], hbuf, N, Ks[layer]);
        gat_fused<<<fusedBlocks, 256, 0, stream>>>(hbuf, offsets, recs, easrt, winStart,
                                                   Wes[layer], atts[layer], bis[layer],
                                                   acth, (layer == 2) ? dout : nullptr, N, R);
    }
}